// Round 3
// baseline (170.870 us; speedup 1.0000x reference)
//
#include <hip/hip_runtime.h>
#include <math.h>

#define NN 512
#define HW (512*512)
#define CH 3

// D[k][n] = s_k * cos(pi*(2n+1)*k/(2N)); also zero the atomic accumulators.
__global__ void k_computeD_zero(float* __restrict__ Dm, float* __restrict__ Tr,
                                float* __restrict__ Tc, float* __restrict__ Gr,
                                float* __restrict__ Gc) {
    int idx = blockIdx.x * blockDim.x + threadIdx.x;   // 0..262143
    int k = idx >> 9, n = idx & 511;
    int m = ((2 * n + 1) * k) & 2047;                  // exact reduction mod 4N
    float s = (k == 0) ? 0.04419417382415922f          // sqrt(1/512)
                       : 0.0625f;                      // sqrt(2/512)
    Dm[idx] = s * cospif((float)m * (1.0f / 1024.0f));
    Tr[idx] = 0.f; Tc[idx] = 0.f; Gr[idx] = 0.f; Gc[idx] = 0.f;
}

// T_row[h][wp] = sum_hp D[hp][h]*att[hp][wp]*rw[hp]
// T_col[h][wp] = cw[wp] * sum_hp D[hp][h]*att[hp][wp]
// Grid 512 blocks: bx = hp_chunk(8) | wp_tile(4)<<3 | h_tile(16)<<5.
// Thread computes 4h x 4wp over a 64-long hp chunk; atomicAdd partials.
__global__ void k_stageA(const float* __restrict__ Dm, const float* __restrict__ att,
                         const float* __restrict__ rw, const float* __restrict__ cw,
                         float* __restrict__ Tr, float* __restrict__ Tc) {
    int bx = blockIdx.x;
    int hp0 = (bx & 7) * 64;
    int wp0b = ((bx >> 3) & 3) * 128;
    int h0b = (bx >> 5) * 32;
    int wl = threadIdx.x & 31, hl = threadIdx.x >> 5;
    int wp0 = wp0b + wl * 4;
    int h0 = h0b + hl * 4;

    float ar[4][4] = {{0.f}}, as[4][4] = {{0.f}};
    for (int g = 0; g < 16; ++g) {
        int hp = hp0 + g * 4;
        float aa[4][4], dd[4][4], rr[4];
        #pragma unroll
        for (int k = 0; k < 4; ++k) {
            *reinterpret_cast<float4*>(aa[k]) =
                *reinterpret_cast<const float4*>(att + (hp + k) * NN + wp0);
            *reinterpret_cast<float4*>(dd[k]) =
                *reinterpret_cast<const float4*>(Dm + (hp + k) * NN + h0);
        }
        *reinterpret_cast<float4*>(rr) = *reinterpret_cast<const float4*>(rw + hp);
        #pragma unroll
        for (int k = 0; k < 4; ++k) {
            float r = rr[k];
            #pragma unroll
            for (int i = 0; i < 4; ++i) {
                float d = dd[k][i];
                float dr = d * r;
                #pragma unroll
                for (int j = 0; j < 4; ++j) {
                    ar[i][j] += dr * aa[k][j];
                    as[i][j] += d * aa[k][j];
                }
            }
        }
    }
    float c4[4];
    *reinterpret_cast<float4*>(c4) = *reinterpret_cast<const float4*>(cw + wp0);
    #pragma unroll
    for (int i = 0; i < 4; ++i)
        #pragma unroll
        for (int j = 0; j < 4; ++j) {
            atomicAdd(&Tr[(h0 + i) * NN + wp0 + j], ar[i][j]);
            atomicAdd(&Tc[(h0 + i) * NN + wp0 + j], as[i][j] * c4[j]);
        }
}

// G[h][w] = sum_wp T[h][wp] * D[wp][w]
// Grid 512 blocks: bx = wp_chunk(8) | w_tile(4)<<3 | h_tile(16)<<5.
__global__ void k_stageB(const float* __restrict__ Dm, const float* __restrict__ Tr,
                         const float* __restrict__ Tc, float* __restrict__ Gr,
                         float* __restrict__ Gc) {
    int bx = blockIdx.x;
    int wp0c = (bx & 7) * 64;
    int w0b = ((bx >> 3) & 3) * 128;
    int h0b = (bx >> 5) * 32;
    int wl = threadIdx.x & 31, hl = threadIdx.x >> 5;
    int w0 = w0b + wl * 4;
    int h0 = h0b + hl * 4;

    float gr[4][4] = {{0.f}}, gc[4][4] = {{0.f}};
    for (int g = 0; g < 16; ++g) {
        int wp = wp0c + g * 4;
        float tr[4][4], tc[4][4], dd[4][4];   // tr[i][k], dd[k][j]
        #pragma unroll
        for (int i = 0; i < 4; ++i) {
            *reinterpret_cast<float4*>(tr[i]) =
                *reinterpret_cast<const float4*>(Tr + (h0 + i) * NN + wp);
            *reinterpret_cast<float4*>(tc[i]) =
                *reinterpret_cast<const float4*>(Tc + (h0 + i) * NN + wp);
        }
        #pragma unroll
        for (int k = 0; k < 4; ++k)
            *reinterpret_cast<float4*>(dd[k]) =
                *reinterpret_cast<const float4*>(Dm + (wp + k) * NN + w0);
        #pragma unroll
        for (int k = 0; k < 4; ++k)
            #pragma unroll
            for (int i = 0; i < 4; ++i) {
                float a = tr[i][k], b = tc[i][k];
                #pragma unroll
                for (int j = 0; j < 4; ++j) {
                    gr[i][j] += a * dd[k][j];
                    gc[i][j] += b * dd[k][j];
                }
            }
    }
    #pragma unroll
    for (int i = 0; i < 4; ++i)
        #pragma unroll
        for (int j = 0; j < 4; ++j) {
            atomicAdd(&Gr[(h0 + i) * NN + w0 + j], gr[i][j]);
            atomicAdd(&Gc[(h0 + i) * NN + w0 + j], gc[i][j]);
        }
}

// Per b: acc_row = sum_{c,hw} x[b,c,hw]*Gr[hw], acc_col same with Gc.
__global__ void k_reduce(const float* __restrict__ x, const float* __restrict__ Gr,
                         const float* __restrict__ Gc, float* __restrict__ partials) {
    int b = blockIdx.y;
    int blk = blockIdx.x;          // 0..15
    int t = threadIdx.x;           // 0..255
    const float* xb = x + (size_t)b * (CH * HW);
    int hw0 = blk * (HW / 16);     // 16384-wide chunk
    float accr = 0.f, accc = 0.f;
    #pragma unroll 4
    for (int j = 0; j < 16; ++j) {
        int hw = hw0 + j * 1024 + t * 4;
        float4 gr = *(const float4*)(Gr + hw);
        float4 gc = *(const float4*)(Gc + hw);
        float4 x0 = *(const float4*)(xb + hw);
        float4 x1 = *(const float4*)(xb + HW + hw);
        float4 x2 = *(const float4*)(xb + 2 * HW + hw);
        float sxx = x0.x + x1.x + x2.x;
        float sxy = x0.y + x1.y + x2.y;
        float sxz = x0.z + x1.z + x2.z;
        float sxw = x0.w + x1.w + x2.w;
        accr += gr.x * sxx + gr.y * sxy + gr.z * sxz + gr.w * sxw;
        accc += gc.x * sxx + gc.y * sxy + gc.z * sxz + gc.w * sxw;
    }
    for (int off = 32; off > 0; off >>= 1) {
        accr += __shfl_down(accr, off);
        accc += __shfl_down(accc, off);
    }
    __shared__ float sr[4], sc[4];
    int wid = t >> 6;
    if ((t & 63) == 0) { sr[wid] = accr; sc[wid] = accc; }
    __syncthreads();
    if (t == 0) {
        float r = sr[0] + sr[1] + sr[2] + sr[3];
        float c = sc[0] + sc[1] + sc[2] + sc[3];
        partials[(b * 16 + blk) * 2 + 0] = r;
        partials[(b * 16 + blk) * 2 + 1] = c;
    }
}

__global__ void k_final(const float* __restrict__ partials, float* __restrict__ out) {
    int b = threadIdx.x;   // 0..63
    float r = 0.f, c = 0.f;
    for (int i = 0; i < 16; ++i) {
        r += partials[(b * 16 + i) * 2 + 0];
        c += partials[(b * 16 + i) * 2 + 1];
    }
    const float inv = 1.0f / (float)(CH * HW);   // 1/786432
    r *= inv; c *= inv;
    out[b * 2 + 0] = 1.0f / (1.0f + expf(-c));   // col_out first (stack order)
    out[b * 2 + 1] = 1.0f / (1.0f + expf(-r));
}

extern "C" void kernel_launch(void* const* d_in, const int* in_sizes, int n_in,
                              void* d_out, int out_size, void* d_ws, size_t ws_size,
                              hipStream_t stream) {
    const float* x   = (const float*)d_in[0];   // [64,3,512,512]
    const float* att = (const float*)d_in[1];   // [512,512]
    const float* rw  = (const float*)d_in[2];   // [512]
    const float* cw  = (const float*)d_in[3];   // [512]
    float* out = (float*)d_out;                 // [64,2]

    float* ws = (float*)d_ws;
    float* Dm = ws;                 // 262144
    float* Tr = ws + 1 * HW;
    float* Tc = ws + 2 * HW;
    float* Gr = ws + 3 * HW;
    float* Gc = ws + 4 * HW;
    float* partials = ws + 5 * HW;  // 64*16*2 = 2048

    k_computeD_zero<<<1024, 256, 0, stream>>>(Dm, Tr, Tc, Gr, Gc);
    k_stageA<<<512, 256, 0, stream>>>(Dm, att, rw, cw, Tr, Tc);
    k_stageB<<<512, 256, 0, stream>>>(Dm, Tr, Tc, Gr, Gc);
    dim3 g(16, 64);
    k_reduce<<<g, 256, 0, stream>>>(x, Gr, Gc, partials);
    k_final<<<1, 64, 0, stream>>>(partials, out);
}